// Round 11
// baseline (156.500 us; speedup 1.0000x reference)
//
#include <hip/hip_runtime.h>

// MoE dense: N=16384, D=256, E=8, H=128.
// R11: fused experts kernel (R4 dataflow + all later fixes). 512 blocks x 32
// rows = 2 blocks/CU (R4 was 256 = 1/CU -> 120us); x K=256 LDS-resident;
// XOR-swizzled Xs/Hs/Bs; h' never leaves LDS -> hw buffer, stage2 GEMM
// (17.7 GFLOP of pure combine overhead) and k_add all deleted.
// Workspace (~11 MB):
//   xb   [16384][256] bf16 @ 0
//   w1t  [8][256][256] bf16 @ 8388608   (w1t[e][h][k] = W1[e][k][h])
//   wg1t [128][256] bf16 @ 9437184      (wg1t[h][k] = Wg1[k][h])
//   w2te [8][256][256] bf16 @ 9502720   (w2te[e][d][h] = W2[e][h][d])
//   g    [16384][8] f32 @ 10551296

typedef unsigned short USH;
typedef float f32x4 __attribute__((ext_vector_type(4)));
typedef __bf16 bf16x8 __attribute__((ext_vector_type(8)));

#define AS1 __attribute__((address_space(1)))
#define AS3 __attribute__((address_space(3)))

__device__ __forceinline__ USH f2bf(float f) {
  unsigned int u = __float_as_uint(f);
  u += 0x7fffu + ((u >> 16) & 1u);   // RNE
  return (USH)(u >> 16);
}

__device__ __forceinline__ void gl2lds16(const void* g, void* l) {
  __builtin_amdgcn_global_load_lds((AS1 const void*)g, (AS3 void*)l, 16, 0, 0);
}

// ---------------- prep ----------------
// blocks: [0,2048) xb | [2048,2176) w1t-T | [2176,2184) wg1t-T | [2184,2312) w2te-T

__global__ __launch_bounds__(256) void k_prep(
    const float* __restrict__ x,
    const float* __restrict__ Wg1,
    const float* __restrict__ W1,
    const float* __restrict__ W2,
    USH* __restrict__ xb, USH* __restrict__ wg1t,
    USH* __restrict__ w1t, USH* __restrict__ w2te) {
  __shared__ float T[64][65];
  int b = blockIdx.x, tid = threadIdx.x;

  if (b < 2048) {               // xb: flat coalesced cast
    size_t i8 = ((size_t)b * 256 + tid) * 8;
    float4 a = *(const float4*)(x + i8);
    float4 c = *(const float4*)(x + i8 + 4);
    USH v[8];
    v[0] = f2bf(a.x); v[1] = f2bf(a.y); v[2] = f2bf(a.z); v[3] = f2bf(a.w);
    v[4] = f2bf(c.x); v[5] = f2bf(c.y); v[6] = f2bf(c.z); v[7] = f2bf(c.w);
    *(uint4*)(xb + i8) = *(const uint4*)v;
  } else if (b < 2176) {        // w1t[e][h][k] = W1[e][k][h]
    int bp = b - 2048;
    int e = bp >> 4, tl = bp & 15;
    int c0 = (tl >> 2) * 64, h0 = (tl & 3) * 64;
    const float* src = W1 + (size_t)e * 65536;
#pragma unroll
    for (int p = 0; p < 4; ++p) {
      int r = p * 16 + (tid >> 4), d4 = (tid & 15) * 4;
      float4 v = *(const float4*)(src + (size_t)(c0 + r) * 256 + h0 + d4);
      T[r][d4] = v.x; T[r][d4 + 1] = v.y; T[r][d4 + 2] = v.z; T[r][d4 + 3] = v.w;
    }
    __syncthreads();
#pragma unroll
    for (int p = 0; p < 4; ++p) {
      int hr = p * 16 + (tid >> 4), c4 = (tid & 15) * 4;
      USH w[4];
#pragma unroll
      for (int j = 0; j < 4; ++j) w[j] = f2bf(T[c4 + j][hr]);
      *(uint2*)(w1t + (size_t)e * 65536 + (size_t)(h0 + hr) * 256 + c0 + c4) = *(const uint2*)w;
    }
  } else if (b < 2184) {        // wg1t[h][k] = Wg1[k][h]
    int bp = b - 2176;
    int c0 = (bp >> 1) * 64, h0 = (bp & 1) * 64;
#pragma unroll
    for (int p = 0; p < 4; ++p) {
      int r = p * 16 + (tid >> 4), d4 = (tid & 15) * 4;
      float4 v = *(const float4*)(Wg1 + (size_t)(c0 + r) * 128 + h0 + d4);
      T[r][d4] = v.x; T[r][d4 + 1] = v.y; T[r][d4 + 2] = v.z; T[r][d4 + 3] = v.w;
    }
    __syncthreads();
#pragma unroll
    for (int p = 0; p < 4; ++p) {
      int hr = p * 16 + (tid >> 4), c4 = (tid & 15) * 4;
      USH w[4];
#pragma unroll
      for (int j = 0; j < 4; ++j) w[j] = f2bf(T[c4 + j][hr]);
      *(uint2*)(wg1t + (size_t)(h0 + hr) * 256 + c0 + c4) = *(const uint2*)w;
    }
  } else {                      // w2te[e][d][h] = W2[e][h][d]
    int bp = b - 2184;
    int e = bp >> 4, tl = bp & 15;
    int h0 = (tl >> 2) * 64, d0 = (tl & 3) * 64;
    const float* src = W2 + (size_t)e * 65536;
#pragma unroll
    for (int p = 0; p < 4; ++p) {
      int r = p * 16 + (tid >> 4), d4 = (tid & 15) * 4;
      float4 v = *(const float4*)(src + (size_t)(h0 + r) * 256 + d0 + d4);
      T[r][d4] = v.x; T[r][d4 + 1] = v.y; T[r][d4 + 2] = v.z; T[r][d4 + 3] = v.w;
    }
    __syncthreads();
#pragma unroll
    for (int p = 0; p < 4; ++p) {
      int dr = p * 16 + (tid >> 4), h4 = (tid & 15) * 4;
      USH w[4];
#pragma unroll
      for (int j = 0; j < 4; ++j) w[j] = f2bf(T[h4 + j][dr]);
      *(uint2*)(w2te + (size_t)e * 65536 + (size_t)(d0 + dr) * 256 + h0 + h4) = *(const uint2*)w;
    }
  }
}

// ---------------- gate (R8 structure; writes g only) ----------------

__global__ __launch_bounds__(256) void k_gate(const USH* __restrict__ xb,
                                              const USH* __restrict__ wg1t,
                                              const float* __restrict__ bg1,
                                              const float* __restrict__ wg2,
                                              const float* __restrict__ bg2,
                                              float* __restrict__ g) {
  __shared__ __align__(16) USH As[32 * 64];
  __shared__ __align__(16) USH Bs[128 * 64];
  __shared__ float hg[32 * 129];
  __shared__ float bg1s[128];
  __shared__ float w2s[128 * 8];
  __shared__ float b2s[8];
  __shared__ float lg[32 * 8];

  int tid = threadIdx.x;
  int wave = tid >> 6, lane = tid & 63;
  int quad = lane >> 4, l16 = lane & 15;
  int sw = l16 & 7;
  int wr = wave >> 1, wc = wave & 1;
  int rowBase = blockIdx.x * 32;

  for (int t = tid; t < 1024; t += 256) w2s[t] = wg2[t];
  if (tid < 8) b2s[tid] = bg2[tid];
  if (tid < 128) bg1s[tid] = bg1[tid];

  f32x4 acc[4] = {};
  for (int kt = 0; kt < 4; ++kt) {
    int kb = kt * 64;
    {
      int r = tid >> 3, c8 = (tid & 7) ^ (r & 7);
      gl2lds16(xb + (size_t)(rowBase + r) * 256 + kb + c8 * 8, As + (size_t)tid * 8);
    }
#pragma unroll
    for (int c = 0; c < 4; ++c) {
      int i = c * 256 + tid;
      int r = i >> 3, c8 = (i & 7) ^ (r & 7);
      gl2lds16(wg1t + (size_t)r * 256 + kb + c8 * 8, Bs + (size_t)i * 8);
    }
    __syncthreads();
#pragma unroll
    for (int kkc = 0; kkc < 8; kkc += 4) {
      bf16x8 av = *(const bf16x8*)(As + (wr * 16 + l16) * 64 + (((kkc + quad) ^ sw) * 8));
#pragma unroll
      for (int j = 0; j < 4; ++j) {
        bf16x8 bv = *(const bf16x8*)(Bs + (wc * 64 + j * 16 + l16) * 64 + (((kkc + quad) ^ sw) * 8));
        acc[j] = __builtin_amdgcn_mfma_f32_16x16x32_bf16(av, bv, acc[j], 0, 0, 0);
      }
    }
    __syncthreads();
  }

#pragma unroll
  for (int j = 0; j < 4; ++j)
#pragma unroll
    for (int r = 0; r < 4; ++r) {
      int row = wr * 16 + quad * 4 + r;
      int col = wc * 64 + j * 16 + l16;
      hg[row * 129 + col] = fmaxf(acc[j][r] + bg1s[col], 0.0f);
    }
  __syncthreads();

  {
    int row = tid >> 3, p = tid & 7;
    float s = b2s[p];
    for (int k = 0; k < 128; ++k) s += hg[row * 129 + k] * w2s[k * 8 + p];
    lg[row * 8 + p] = s;
  }
  __syncthreads();

  if (tid < 32) {
    float l[8];
    float m = -1e30f;
#pragma unroll
    for (int e = 0; e < 8; ++e) { l[e] = lg[tid * 8 + e]; m = fmaxf(m, l[e]); }
    float s = 0.0f;
#pragma unroll
    for (int e = 0; e < 8; ++e) { l[e] = expf(l[e] - m); s += l[e]; }
    float inv = 1.0f / s;
    size_t grow = rowBase + tid;
#pragma unroll
    for (int e = 0; e < 8; ++e) g[grow * 8 + e] = l[e] * inv;
  }
}

// ---------------- fused experts ----------------
// out[n] = sum_e g[n,e]*(relu(x@W1e^T + b1e)@W2e^T + b2e)
// 512 blocks x 32 rows; wave owns 64 output cols; acc_out persists in VGPRs.
// LDS: Xs 16K (resident, K=256) + Hs 16K + Bs 32K = 64K -> 2 blocks/CU.

__global__ __launch_bounds__(256) void k_experts(const USH* __restrict__ xb,
                                                 const USH* __restrict__ w1t,
                                                 const USH* __restrict__ w2te,
                                                 const float* __restrict__ g,
                                                 const float* __restrict__ b1,
                                                 const float* __restrict__ b2,
                                                 float* __restrict__ out) {
  __shared__ __align__(16) USH Xs[32 * 256];
  __shared__ __align__(16) USH Hs[32 * 256];
  __shared__ __align__(16) USH Bs[256 * 64];
  __shared__ float gs[32];

  int tid = threadIdx.x;
  int wave = tid >> 6, lane = tid & 63;
  int quad = lane >> 4, l16 = lane & 15;
  int sw = l16 & 7;
  int rowBase = blockIdx.x * 32;

  // stage x (all K=256) once; chunk c of row r at slot c^(r&7) (low 3 bits)
#pragma unroll
  for (int p = 0; p < 4; ++p) {
    int i = p * 256 + tid;
    int r = i >> 5, c = (i & 31) ^ (r & 7);
    gl2lds16(xb + (size_t)(rowBase + r) * 256 + c * 8, Xs + (size_t)i * 8);
  }

  f32x4 acc_out[2][4] = {};

  for (int e = 0; e < 8; ++e) {
    __syncthreads();   // gs/Hs/Bs overwrite guard; e==0: Xs ready
    if (tid < 32) gs[tid] = g[(size_t)(rowBase + tid) * 8 + e];
    const USH* W1e = w1t + (size_t)e * 65536;
    const USH* W2e = w2te + (size_t)e * 65536;

    // ---- L1: h = x @ W1e^T ----
    f32x4 acc_h[2][4] = {};
    for (int kt = 0; kt < 4; ++kt) {
#pragma unroll
      for (int p = 0; p < 8; ++p) {
        int i = p * 256 + tid;
        int r = i >> 3, c = (i & 7) ^ (r & 7);
        gl2lds16(W1e + (size_t)r * 256 + kt * 64 + c * 8, Bs + (size_t)i * 8);
      }
      __syncthreads();
#pragma unroll
      for (int kh = 0; kh < 2; ++kh) {
        int w = kt * 2 + kh;
        bf16x8 av[2], bv[4];
#pragma unroll
        for (int rt = 0; rt < 2; ++rt)
          av[rt] = *(const bf16x8*)(Xs + ((rt * 16 + l16) * 32 + ((w * 4 + quad) ^ sw)) * 8);
#pragma unroll
        for (int ct = 0; ct < 4; ++ct)
          bv[ct] = *(const bf16x8*)(Bs + ((wave * 64 + ct * 16 + l16) * 8 + ((kh * 4 + quad) ^ sw)) * 8);
#pragma unroll
        for (int rt = 0; rt < 2; ++rt)
#pragma unroll
          for (int ct = 0; ct < 4; ++ct)
            acc_h[rt][ct] = __builtin_amdgcn_mfma_f32_16x16x32_bf16(av[rt], bv[ct], acc_h[rt][ct], 0, 0, 0);
      }
      __syncthreads();
    }

    // ---- h' = g*relu(h+b1) -> Hs ----
#pragma unroll
    for (int rt = 0; rt < 2; ++rt)
#pragma unroll
      for (int rr = 0; rr < 4; ++rr) {
        int hr = rt * 16 + quad * 4 + rr;
        float gg = gs[hr];
#pragma unroll
        for (int ct = 0; ct < 4; ++ct) {
          int col = wave * 64 + ct * 16 + l16;
          float v = fmaxf(acc_h[rt][ct][rr] + b1[e * 256 + col], 0.0f) * gg;
          Hs[hr * 256 + (((col >> 3) ^ (hr & 7)) * 8) + (col & 7)] = f2bf(v);
        }
      }
    __syncthreads();

    // ---- L2: acc_out += h' @ W2e^T ----
    for (int kt = 0; kt < 4; ++kt) {
#pragma unroll
      for (int p = 0; p < 8; ++p) {
        int i = p * 256 + tid;
        int r = i >> 3, c = (i & 7) ^ (r & 7);
        gl2lds16(W2e + (size_t)r * 256 + kt * 64 + c * 8, Bs + (size_t)i * 8);
      }
      __syncthreads();
#pragma unroll
      for (int kh = 0; kh < 2; ++kh) {
        int w = kt * 2 + kh;
        bf16x8 av[2], bv[4];
#pragma unroll
        for (int rt = 0; rt < 2; ++rt)
          av[rt] = *(const bf16x8*)(Hs + ((rt * 16 + l16) * 32 + ((w * 4 + quad) ^ sw)) * 8);
#pragma unroll
        for (int ct = 0; ct < 4; ++ct)
          bv[ct] = *(const bf16x8*)(Bs + ((wave * 64 + ct * 16 + l16) * 8 + ((kh * 4 + quad) ^ sw)) * 8);
#pragma unroll
        for (int rt = 0; rt < 2; ++rt)
#pragma unroll
          for (int ct = 0; ct < 4; ++ct)
            acc_out[rt][ct] = __builtin_amdgcn_mfma_f32_16x16x32_bf16(av[rt], bv[ct], acc_out[rt][ct], 0, 0, 0);
      }
      __syncthreads();
    }

    // ---- + g*b2 ----
#pragma unroll
    for (int ct = 0; ct < 4; ++ct) {
      float b2c = b2[e * 256 + wave * 64 + ct * 16 + l16];
#pragma unroll
      for (int rt = 0; rt < 2; ++rt)
#pragma unroll
        for (int rr = 0; rr < 4; ++rr)
          acc_out[rt][ct][rr] += gs[rt * 16 + quad * 4 + rr] * b2c;
    }
  }

  // ---- final store ----
#pragma unroll
  for (int rt = 0; rt < 2; ++rt)
#pragma unroll
    for (int rr = 0; rr < 4; ++rr) {
      size_t grow = (size_t)(rowBase + rt * 16 + quad * 4 + rr);
#pragma unroll
      for (int ct = 0; ct < 4; ++ct)
        out[grow * 256 + wave * 64 + ct * 16 + l16] = acc_out[rt][ct][rr];
    }
}

// ---------------- launch ----------------

extern "C" void kernel_launch(void* const* d_in, const int* in_sizes, int n_in,
                              void* d_out, int out_size, void* d_ws, size_t ws_size,
                              hipStream_t stream) {
  const float* x   = (const float*)d_in[0];
  const float* Wg1 = (const float*)d_in[1];
  const float* bg1 = (const float*)d_in[2];
  const float* Wg2 = (const float*)d_in[3];
  const float* bg2 = (const float*)d_in[4];
  const float* W1  = (const float*)d_in[5];
  const float* b1  = (const float*)d_in[6];
  const float* W2  = (const float*)d_in[7];
  const float* b2  = (const float*)d_in[8];
  float* out = (float*)d_out;

  char* ws = (char*)d_ws;
  USH*   xb    = (USH*)(ws);
  USH*   w1t   = (USH*)(ws + 8388608);
  USH*   wg1t  = (USH*)(ws + 9437184);
  USH*   w2te  = (USH*)(ws + 9502720);
  float* g     = (float*)(ws + 10551296);   // total ~11 MB

  hipLaunchKernelGGL(k_prep, dim3(2312), dim3(256), 0, stream,
                     x, Wg1, W1, W2, xb, wg1t, w1t, w2te);
  hipLaunchKernelGGL(k_gate,    dim3(512), dim3(256), 0, stream, xb, wg1t, bg1, Wg2, bg2, g);
  hipLaunchKernelGGL(k_experts, dim3(512), dim3(256), 0, stream, xb, w1t, w2te, g, b1, b2, out);
}